// Round 1
// baseline (374.809 us; speedup 1.0000x reference)
//
#include <hip/hip_runtime.h>

#define HID 128

// h = (x @ W^T + b) / 256   -> h[N][128] into workspace
__global__ __launch_bounds__(256) void proj_kernel(
    const float* __restrict__ x, const float* __restrict__ W,
    const float* __restrict__ b, float* __restrict__ h, int N) {
  __shared__ float Wl[HID * 129];   // padded stride 129: 2-way bank alias (free)
  __shared__ float bl[HID];
  __shared__ float xl[16][HID];

  const int tid = threadIdx.x;
  for (int i = tid; i < HID * HID; i += 256) {
    Wl[(i >> 7) * 129 + (i & 127)] = W[i];
  }
  if (tid < HID) bl[tid] = b[tid];

  const int j = tid & 127;   // output column
  const int rh = tid >> 7;   // row-half: 0 or 1 (8 rows each)

  for (int base = blockIdx.x * 16; base < N; base += gridDim.x * 16) {
    __syncthreads();
    for (int i = tid; i < 16 * HID; i += 256) {
      int r = i >> 7, c = i & 127;
      int row = base + r;
      xl[r][c] = (row < N) ? x[(size_t)row * HID + c] : 0.0f;
    }
    __syncthreads();

    float acc[8] = {0.f, 0.f, 0.f, 0.f, 0.f, 0.f, 0.f, 0.f};
    const float* wrow = &Wl[j * 129];
    const float(*xr)[HID] = &xl[rh * 8];
#pragma unroll 4
    for (int k = 0; k < HID; ++k) {
      float wv = wrow[k];
#pragma unroll
      for (int r = 0; r < 8; ++r) acc[r] += wv * xr[r][k];
    }
    float bb = bl[j];
#pragma unroll
    for (int r = 0; r < 8; ++r) {
      int row = base + rh * 8 + r;
      if (row < N) h[(size_t)row * HID + j] = (acc[r] + bb) * (1.0f / 256.0f);
    }
  }
}

// out[e][c][:] = (v[e][c][:] + u[e][c] * (h[src[e]] - h[dst[e]])) * 0.5
// one thread per (edge, quad-of-4-columns): 32 threads cover an edge.
__global__ __launch_bounds__(256) void edge_kernel(
    const float* __restrict__ v, const float* __restrict__ u,
    const int* __restrict__ src, const int* __restrict__ dst,
    const float* __restrict__ h, float* __restrict__ out, int E) {
  int idx = blockIdx.x * 256 + threadIdx.x;
  int e = idx >> 5;
  if (e >= E) return;
  int q = idx & 31;

  int s = src[e];
  int d = dst[e];

  const float4* hs = (const float4*)(h + (size_t)s * HID);
  const float4* hd = (const float4*)(h + (size_t)d * HID);
  float4 a = hs[q];
  float4 bq = hd[q];
  float4 phi;
  phi.x = a.x - bq.x;
  phi.y = a.y - bq.y;
  phi.z = a.z - bq.z;
  phi.w = a.w - bq.w;

  float u0 = u[(size_t)e * 3 + 0];
  float u1 = u[(size_t)e * 3 + 1];
  float u2 = u[(size_t)e * 3 + 2];

  const float4* vp = (const float4*)(v + (size_t)e * 3 * HID);
  float4* op = (float4*)(out + (size_t)e * 3 * HID);

  float4 v0 = vp[q];
  float4 v1 = vp[32 + q];
  float4 v2 = vp[64 + q];

  float4 o0, o1, o2;
  o0.x = (v0.x + u0 * phi.x) * 0.5f;
  o0.y = (v0.y + u0 * phi.y) * 0.5f;
  o0.z = (v0.z + u0 * phi.z) * 0.5f;
  o0.w = (v0.w + u0 * phi.w) * 0.5f;
  o1.x = (v1.x + u1 * phi.x) * 0.5f;
  o1.y = (v1.y + u1 * phi.y) * 0.5f;
  o1.z = (v1.z + u1 * phi.z) * 0.5f;
  o1.w = (v1.w + u1 * phi.w) * 0.5f;
  o2.x = (v2.x + u2 * phi.x) * 0.5f;
  o2.y = (v2.y + u2 * phi.y) * 0.5f;
  o2.z = (v2.z + u2 * phi.z) * 0.5f;
  o2.w = (v2.w + u2 * phi.w) * 0.5f;

  op[q] = o0;
  op[32 + q] = o1;
  op[64 + q] = o2;
}

extern "C" void kernel_launch(void* const* d_in, const int* in_sizes, int n_in,
                              void* d_out, int out_size, void* d_ws, size_t ws_size,
                              hipStream_t stream) {
  const float* x = (const float*)d_in[0];
  const float* v = (const float*)d_in[1];
  const float* u = (const float*)d_in[2];
  const float* W = (const float*)d_in[3];
  const float* b = (const float*)d_in[4];
  const int* src = (const int*)d_in[5];
  const int* dst = (const int*)d_in[6];
  float* out = (float*)d_out;

  const int N = in_sizes[0] / HID;       // 50000
  const int E = in_sizes[5];             // 500000

  float* h = (float*)d_ws;               // N*HID floats = 25.6 MB

  int proj_blocks = (N + 15) / 16;
  proj_kernel<<<proj_blocks, 256, 0, stream>>>(x, W, b, h, N);

  long long total = (long long)E * 32;
  int edge_blocks = (int)((total + 255) / 256);
  edge_kernel<<<edge_blocks, 256, 0, stream>>>(v, u, src, dst, h, out, E);
}

// Round 2
// 330.429 us; speedup vs baseline: 1.1343x; 1.1343x over previous
//
#include <hip/hip_runtime.h>

#define HID 128

typedef __attribute__((ext_vector_type(8))) short bf16x8;
typedef __attribute__((ext_vector_type(4))) float f32x4;

static __device__ inline bf16x8 cvt8(float4 lo, float4 hi) {
  bf16x8 r;
  float vals[8] = {lo.x, lo.y, lo.z, lo.w, hi.x, hi.y, hi.z, hi.w};
#pragma unroll
  for (int i = 0; i < 8; ++i) {
    unsigned uu = __builtin_bit_cast(unsigned, vals[i]);
    uu = (uu + 0x7fffu + ((uu >> 16) & 1u)) >> 16;
    r[i] = (short)uu;
  }
  return r;
}

// h = (x @ W^T + b) / 256 via MFMA bf16.
// One wave computes a 16-row x 128-col tile of h. nTiles = N/16 (N % 16 == 0).
__global__ __launch_bounds__(256) void proj_mfma(
    const float* __restrict__ x, const float* __restrict__ W,
    const float* __restrict__ b, float* __restrict__ h, int nTiles) {
  int wave = (int)((blockIdx.x * 256 + threadIdx.x) >> 6);
  if (wave >= nTiles) return;
  int lane = threadIdx.x & 63;
  int m0 = wave * 16;
  int row = lane & 15;  // A row within tile / B (=W) row within n-tile / C col
  int kg = lane >> 4;   // k-group 0..3 (8 elements each within a 32-k step)

  // A fragments: x[m0+row][s*32 + kg*8 .. +7], s = 0..3
  bf16x8 afrag[4];
  const float* xrow = x + (size_t)(m0 + row) * HID + kg * 8;
#pragma unroll
  for (int s = 0; s < 4; ++s) {
    float4 lo = *(const float4*)(xrow + s * 32);
    float4 hi = *(const float4*)(xrow + s * 32 + 4);
    afrag[s] = cvt8(lo, hi);
  }

  int crow0 = kg * 4;  // C rows (lane>>4)*4 + reg
#pragma unroll
  for (int nt = 0; nt < 8; ++nt) {
    int n0 = nt * 16;
    f32x4 acc = {0.f, 0.f, 0.f, 0.f};
    const float* wrow = W + (size_t)(n0 + row) * HID + kg * 8;
#pragma unroll
    for (int s = 0; s < 4; ++s) {
      float4 lo = *(const float4*)(wrow + s * 32);
      float4 hi = *(const float4*)(wrow + s * 32 + 4);
      bf16x8 bfrag = cvt8(lo, hi);
      acc = __builtin_amdgcn_mfma_f32_16x16x32_bf16(afrag[s], bfrag, acc, 0, 0, 0);
    }
    float bb = b[n0 + row];  // C col = lane&15 = row
    int ccol = n0 + row;
#pragma unroll
    for (int r = 0; r < 4; ++r) {
      h[(size_t)(m0 + crow0 + r) * HID + ccol] = (acc[r] + bb) * (1.0f / 256.0f);
    }
  }
}

// out[e][c][:] = (v[e][c][:] + u[e][c] * (h[src[e]] - h[dst[e]])) * 0.5
// one thread per (edge, quad-of-4-columns): 32 threads cover an edge.
__global__ __launch_bounds__(256) void edge_kernel(
    const float* __restrict__ v, const float* __restrict__ u,
    const int* __restrict__ src, const int* __restrict__ dst,
    const float* __restrict__ h, float* __restrict__ out, int E) {
  int idx = blockIdx.x * 256 + threadIdx.x;
  int e = idx >> 5;
  if (e >= E) return;
  int q = idx & 31;

  int s = src[e];
  int d = dst[e];

  const float4* hs = (const float4*)(h + (size_t)s * HID);
  const float4* hd = (const float4*)(h + (size_t)d * HID);
  float4 a = hs[q];
  float4 bq = hd[q];
  float4 phi;
  phi.x = a.x - bq.x;
  phi.y = a.y - bq.y;
  phi.z = a.z - bq.z;
  phi.w = a.w - bq.w;

  float u0 = u[(size_t)e * 3 + 0];
  float u1 = u[(size_t)e * 3 + 1];
  float u2 = u[(size_t)e * 3 + 2];

  const float4* vp = (const float4*)(v + (size_t)e * 3 * HID);
  float4* op = (float4*)(out + (size_t)e * 3 * HID);

  float4 v0 = vp[q];
  float4 v1 = vp[32 + q];
  float4 v2 = vp[64 + q];

  float4 o0, o1, o2;
  o0.x = (v0.x + u0 * phi.x) * 0.5f;
  o0.y = (v0.y + u0 * phi.y) * 0.5f;
  o0.z = (v0.z + u0 * phi.z) * 0.5f;
  o0.w = (v0.w + u0 * phi.w) * 0.5f;
  o1.x = (v1.x + u1 * phi.x) * 0.5f;
  o1.y = (v1.y + u1 * phi.y) * 0.5f;
  o1.z = (v1.z + u1 * phi.z) * 0.5f;
  o1.w = (v1.w + u1 * phi.w) * 0.5f;
  o2.x = (v2.x + u2 * phi.x) * 0.5f;
  o2.y = (v2.y + u2 * phi.y) * 0.5f;
  o2.z = (v2.z + u2 * phi.z) * 0.5f;
  o2.w = (v2.w + u2 * phi.w) * 0.5f;

  op[q] = o0;
  op[32 + q] = o1;
  op[64 + q] = o2;
}

extern "C" void kernel_launch(void* const* d_in, const int* in_sizes, int n_in,
                              void* d_out, int out_size, void* d_ws, size_t ws_size,
                              hipStream_t stream) {
  const float* x = (const float*)d_in[0];
  const float* v = (const float*)d_in[1];
  const float* u = (const float*)d_in[2];
  const float* W = (const float*)d_in[3];
  const float* b = (const float*)d_in[4];
  const int* src = (const int*)d_in[5];
  const int* dst = (const int*)d_in[6];
  float* out = (float*)d_out;

  const int N = in_sizes[0] / HID;  // 50000
  const int E = in_sizes[5];        // 500000

  float* h = (float*)d_ws;          // N*HID floats = 25.6 MB

  int nTiles = N / 16;              // 3125 (N % 16 == 0)
  int proj_blocks = (nTiles + 3) / 4;  // 4 waves per 256-thread block
  proj_mfma<<<proj_blocks, 256, 0, stream>>>(x, W, b, h, nTiles);

  long long total = (long long)E * 32;
  int edge_blocks = (int)((total + 255) / 256);
  edge_kernel<<<edge_blocks, 256, 0, stream>>>(v, u, src, dst, h, out, E);
}

// Round 3
// 294.782 us; speedup vs baseline: 1.2715x; 1.1209x over previous
//
#include <hip/hip_runtime.h>

#define HID 128

typedef __attribute__((ext_vector_type(8))) short bf16x8;
typedef __attribute__((ext_vector_type(4))) float f32x4;
typedef __attribute__((ext_vector_type(4))) unsigned short u16x4;

static __device__ inline unsigned short f2bf(float f) {
  unsigned uu = __builtin_bit_cast(unsigned, f);
  uu = (uu + 0x7fffu + ((uu >> 16) & 1u)) >> 16;
  return (unsigned short)uu;
}
static __device__ inline float bf2f(unsigned short s) {
  return __builtin_bit_cast(float, ((unsigned)s) << 16);
}

static __device__ inline bf16x8 cvt8(float4 lo, float4 hi) {
  bf16x8 r;
  float vals[8] = {lo.x, lo.y, lo.z, lo.w, hi.x, hi.y, hi.z, hi.w};
#pragma unroll
  for (int i = 0; i < 8; ++i) r[i] = (short)f2bf(vals[i]);
  return r;
}

// h = (x @ W^T + b) / 256 via MFMA bf16, h stored as bf16.
// One wave computes 64 rows x 128 cols (4 m-tiles share each W fragment).
__global__ __launch_bounds__(256) void proj_mfma(
    const float* __restrict__ x, const float* __restrict__ W,
    const float* __restrict__ b, unsigned short* __restrict__ h, int N) {
  int wave = (int)((blockIdx.x * 256 + threadIdx.x) >> 6);
  int lane = threadIdx.x & 63;
  int m0 = wave * 64;
  if (m0 >= N) return;
  int row = lane & 15;  // A row within m-tile / W row within n-tile / C col
  int kg = lane >> 4;   // k-group 0..3

  // A fragments: x[m0+mt*16+row][s*32 + kg*8 .. +7]
  bf16x8 afrag[4][4];
#pragma unroll
  for (int mt = 0; mt < 4; ++mt) {
    int r = m0 + mt * 16 + row;
    int rc = r < N ? r : N - 1;  // clamp; garbage rows masked at store
    const float* xrow = x + (size_t)rc * HID + kg * 8;
#pragma unroll
    for (int s = 0; s < 4; ++s) {
      float4 lo = *(const float4*)(xrow + s * 32);
      float4 hi = *(const float4*)(xrow + s * 32 + 4);
      afrag[mt][s] = cvt8(lo, hi);
    }
  }

  int crow0 = kg * 4;
#pragma unroll
  for (int nt = 0; nt < 8; ++nt) {
    int n0 = nt * 16;
    f32x4 acc[4];
#pragma unroll
    for (int mt = 0; mt < 4; ++mt) acc[mt] = (f32x4){0.f, 0.f, 0.f, 0.f};
    const float* wrow = W + (size_t)(n0 + row) * HID + kg * 8;
#pragma unroll
    for (int s = 0; s < 4; ++s) {
      float4 lo = *(const float4*)(wrow + s * 32);
      float4 hi = *(const float4*)(wrow + s * 32 + 4);
      bf16x8 bfrag = cvt8(lo, hi);
#pragma unroll
      for (int mt = 0; mt < 4; ++mt)
        acc[mt] = __builtin_amdgcn_mfma_f32_16x16x32_bf16(afrag[mt][s], bfrag, acc[mt], 0, 0, 0);
    }
    float bb = b[n0 + row];
    int ccol = n0 + row;
#pragma unroll
    for (int mt = 0; mt < 4; ++mt) {
#pragma unroll
      for (int r2 = 0; r2 < 4; ++r2) {
        int orow = m0 + mt * 16 + crow0 + r2;
        if (orow < N)
          h[(size_t)orow * HID + ccol] = f2bf((acc[mt][r2] + bb) * (1.0f / 256.0f));
      }
    }
  }
}

// out[e][c][:] = (v[e][c][:] + u[e][c] * (h[src[e]] - h[dst[e]])) * 0.5
// one thread per (edge, quad-of-4-columns): 32 threads cover an edge.
// v loads / out stores are nontemporal (streaming) so h stays cached.
__global__ __launch_bounds__(256) void edge_kernel(
    const float* __restrict__ v, const float* __restrict__ u,
    const int* __restrict__ src, const int* __restrict__ dst,
    const unsigned short* __restrict__ h, float* __restrict__ out, int E) {
  int idx = blockIdx.x * 256 + threadIdx.x;
  int e = idx >> 5;
  if (e >= E) return;
  int q = idx & 31;

  int s = src[e];
  int d = dst[e];

  u16x4 a = *(const u16x4*)(h + (size_t)s * HID + q * 4);
  u16x4 bq = *(const u16x4*)(h + (size_t)d * HID + q * 4);
  float phix = bf2f(a.x) - bf2f(bq.x);
  float phiy = bf2f(a.y) - bf2f(bq.y);
  float phiz = bf2f(a.z) - bf2f(bq.z);
  float phiw = bf2f(a.w) - bf2f(bq.w);

  float u0 = u[(size_t)e * 3 + 0];
  float u1 = u[(size_t)e * 3 + 1];
  float u2 = u[(size_t)e * 3 + 2];

  const f32x4* vp = (const f32x4*)(v + (size_t)e * 3 * HID);
  f32x4* op = (f32x4*)(out + (size_t)e * 3 * HID);

  f32x4 v0 = __builtin_nontemporal_load(vp + q);
  f32x4 v1 = __builtin_nontemporal_load(vp + 32 + q);
  f32x4 v2 = __builtin_nontemporal_load(vp + 64 + q);

  f32x4 o0, o1, o2;
  o0[0] = (v0[0] + u0 * phix) * 0.5f;
  o0[1] = (v0[1] + u0 * phiy) * 0.5f;
  o0[2] = (v0[2] + u0 * phiz) * 0.5f;
  o0[3] = (v0[3] + u0 * phiw) * 0.5f;
  o1[0] = (v1[0] + u1 * phix) * 0.5f;
  o1[1] = (v1[1] + u1 * phiy) * 0.5f;
  o1[2] = (v1[2] + u1 * phiz) * 0.5f;
  o1[3] = (v1[3] + u1 * phiw) * 0.5f;
  o2[0] = (v2[0] + u2 * phix) * 0.5f;
  o2[1] = (v2[1] + u2 * phiy) * 0.5f;
  o2[2] = (v2[2] + u2 * phiz) * 0.5f;
  o2[3] = (v2[3] + u2 * phiw) * 0.5f;

  __builtin_nontemporal_store(o0, op + q);
  __builtin_nontemporal_store(o1, op + 32 + q);
  __builtin_nontemporal_store(o2, op + 64 + q);
}

extern "C" void kernel_launch(void* const* d_in, const int* in_sizes, int n_in,
                              void* d_out, int out_size, void* d_ws, size_t ws_size,
                              hipStream_t stream) {
  const float* x = (const float*)d_in[0];
  const float* v = (const float*)d_in[1];
  const float* u = (const float*)d_in[2];
  const float* W = (const float*)d_in[3];
  const float* b = (const float*)d_in[4];
  const int* src = (const int*)d_in[5];
  const int* dst = (const int*)d_in[6];
  float* out = (float*)d_out;

  const int N = in_sizes[0] / HID;  // 50000
  const int E = in_sizes[5];        // 500000

  unsigned short* h = (unsigned short*)d_ws;  // N*HID bf16 = 12.8 MB

  int nWaves = (N + 63) / 64;              // 782
  int proj_blocks = (nWaves + 3) / 4;      // 4 waves per block
  proj_mfma<<<proj_blocks, 256, 0, stream>>>(x, W, b, h, N);

  long long total = (long long)E * 32;
  int edge_blocks = (int)((total + 255) / 256);
  edge_kernel<<<edge_blocks, 256, 0, stream>>>(v, u, src, dst, h, out, E);
}